// Round 7
// baseline (1247.394 us; speedup 1.0000x reference)
//
#include <hip/hip_runtime.h>

// ============================================================================
// CNF log-density, fused persistent kernel — v8: pipelined operands + VALU diet.
//   - v7 structure kept: DMA ring (4x8KB, global_load_lds, depth-2), counted
//     vmcnt(4) chunk barriers, N-split wave pairs, 32x32x16 val+tan MFMA,
//     bf16 k-slabs, flattened RK machine. (v7 = 774us, MfmaUtil 29.5%)
//   - NEW: software pipeline. Iteration c: stage(c+2); VBAR; ds_read ops(c);
//     MFMA(c-1). LDS read latency retires a full iteration before use ->
//     per-chunk lgkm stall (~40x55cy/feval) off the critical path.
//   - NEW: every VBAR waits lgkmcnt(0) too -> post-transpose/pre-L1 LBARs
//     deleted (ring-slot safety separation unchanged, still barrier-strict).
//   - NEW: VALU diet. v_cvt_pk_bf16_f32 for all f32->bf16 (4 ops/elem -> 0.5);
//     acc init movs gone (first MFMA uses persistent zero C; bias folded into
//     tanh arg via exp2(fma(x, 2log2e, 2log2e*b)), L4 bias added in epilogue).
// ============================================================================

#define DIM   64
#define HID   256
#define BATCH 32768
#define LOG2PI_HALF_SUM 58.8120661251f   // 32 * log(2*pi)

typedef float  floatx4  __attribute__((ext_vector_type(4)));
typedef float  floatx16 __attribute__((ext_vector_type(16)));
typedef short  short8   __attribute__((ext_vector_type(8)));

// ---- workspace: bf16 weights, fragment-linear, contiguous 40 x 8KB chunks --
// chunk c: W1 c0-3, W2 c4-19, W3 c20-35, W4 c36-39. frag = ktile*NT + ntile.
#define BOFF   327680    // biases fp32: b1[256] b2[256] b3[256] b4[64]
#define CHUNK  8192
#define NCHUNK 40

// ---- LDS ----
#define TBS         264              // shorts per tb row (256 + 8 pad)
#define TB_BYTES    16896            // 32 * 264 * 2
#define SLAB_STR    72               // shorts per slab row (64 + 8 pad)
#define SLAB_SH     1152             // shorts per slab (16*72)
#define RING_BYTES  32768            // 4 x 8KB chunk ring
#define GROUP_BYTES 23808            // tb + 3 slabs (16896 + 6912)
#define SMEM_BYTES  (RING_BYTES + 2 * GROUP_BYTES)   // 80384 -> 2 blocks/CU

#define MFMA32(a, b, c) __builtin_amdgcn_mfma_f32_32x32x16_bf16(a, b, c, 0, 0, 0)

// Chunk barrier: counted vmcnt (chunk c landed; c+1,c+2 in flight) + full
// lgkm drain (publishes ds_writes AND retires last iteration's operand reads,
// keeping ring-slot reuse barrier-strict). NEVER vmcnt(0) in the loop.
#define VBAR() do { asm volatile("s_waitcnt vmcnt(4) lgkmcnt(0)" ::: "memory"); \
    __builtin_amdgcn_s_barrier(); __builtin_amdgcn_sched_barrier(0); } while (0)
// DS-visibility barrier: does not touch vmcnt (keeps the count exact).
#define LBAR() do { asm volatile("s_waitcnt lgkmcnt(0)" ::: "memory"); \
    __builtin_amdgcn_s_barrier(); __builtin_amdgcn_sched_barrier(0); } while (0)

__device__ __forceinline__ unsigned cvtpk(float lo, float hi) {
    unsigned r;
    asm("v_cvt_pk_bf16_f32 %0, %1, %2" : "=v"(r) : "v"(lo), "v"(hi));
    return r;
}

__device__ __forceinline__ float bf2f(short s) {
    union { float f; unsigned u; } v;
    v.u = ((unsigned)(unsigned short)s) << 16;
    return v.f;
}

__device__ __forceinline__ float expv(float x) {   // 2^x (VALU interlocked)
    float r; asm("v_exp_f32 %0, %1" : "=v"(r) : "v"(x)); return r;
}

// ---- async global->LDS: 16B/lane, LDS dest = wave-uniform base + lane*16 ----
__device__ __forceinline__ void gld_lds16(const char* g, char* l) {
    __builtin_amdgcn_global_load_lds(
        (const __attribute__((address_space(1))) void*)g,
        (__attribute__((address_space(3))) void*)l, 16, 0, 0);
}

// Stage chunk g into ring slot g%4: each wave DMAs its own 2KB slice (2 ops).
__device__ __forceinline__ void stage_dma(const char* __restrict__ ws, char* ring,
                                          int g, int wave, int lane) {
    const char* src = ws + g * CHUNK + wave * 2048 + lane * 16;
    char* dst = ring + (g & 3) * CHUNK + wave * 2048;
    gld_lds16(src, dst);
    gld_lds16(src + 1024, dst + 1024);
}

// ---- pipelined GEMM segment: chunks GB..GB+NC-1, acc = W-seg * A(tb) ----
// Iteration lc: stage(GB+lc+2); VBAR; read ops(lc); MFMA(lc-1). First MFMA of
// the segment uses z16 (persistent zero C) so acc needs no init movs.
template<int GB, int NC>
__device__ __forceinline__ void gemm_segment(const char* __restrict__ ws, char* ring,
                                             const short* tb, floatx16 (&acc)[4],
                                             const floatx16& z16, int lane, int wave,
                                             int sw, int l31, int hi) {
    short8 Ab[2];
    short8 Bb[2][4];
    const int abase = l31 * TBS + hi * 8;
#pragma unroll
    for (int lc = 0; lc < NC; lc++) {
        stage_dma(ws, ring, GB + lc + 2, wave, lane);     // max 37, no wrap
        VBAR();
        const char* bp = ring + (((GB + lc) & 3) * CHUNK);
        const int bk = lc & 1;
        Ab[bk] = *(const short8*)&tb[abase + lc * 16];
#pragma unroll
        for (int nt = 0; nt < 4; nt++)
            Bb[bk][nt] = *(const short8*)(bp + (sw * 4 + nt) * 1024 + lane * 16);
        if (lc > 0) {
            __builtin_amdgcn_s_setprio(1);
#pragma unroll
            for (int nt = 0; nt < 4; nt++)
                acc[nt] = MFMA32(Ab[bk ^ 1], Bb[bk ^ 1][nt],
                                 (lc == 1) ? z16 : acc[nt]);
            __builtin_amdgcn_s_setprio(0);
        }
    }
    const int bk = (NC - 1) & 1;
    __builtin_amdgcn_s_setprio(1);
#pragma unroll
    for (int nt = 0; nt < 4; nt++)
        acc[nt] = MFMA32(Ab[bk], Bb[bk][nt], acc[nt]);
    __builtin_amdgcn_s_setprio(0);
}

// acc -> tb rows 0-31 (h rows 0-15, t rows 16-31); bias folded into tanh arg:
// tanh(x+b) = 1 - 2/(exp2(fma(x, 2log2e, bsc)) + 1), bsc = 2log2e*b.
__device__ __forceinline__ void transpose_acts(const floatx16 (&acc)[4], short* tb,
                                               const float (&bsc)[4],
                                               int sw, int l31, int hi) {
    unsigned short* tbu = (unsigned short*)tb;
#pragma unroll
    for (int nt = 0; nt < 4; nt++) {
        const int col = sw * 128 + nt * 32 + l31;
        float h[8];
#pragma unroll
        for (int r = 0; r < 8; r++) {
            float e = expv(__builtin_fmaf(acc[nt][r], 2.885390082f, bsc[nt]));
            h[r] = __builtin_fmaf(-2.0f, __builtin_amdgcn_rcpf(e + 1.0f), 1.0f);
        }
#pragma unroll
        for (int p = 0; p < 4; p++) {
            const int r0 = 2 * p, r1 = r0 + 1;
            const int rv0 = (r0 & 3) + 8 * (r0 >> 2) + 4 * hi;
            const int rv1 = (r1 & 3) + 8 * (r1 >> 2) + 4 * hi;
            float t0 = __builtin_fmaf(-h[r0], h[r0], 1.0f) * acc[nt][r0 + 8];
            float t1 = __builtin_fmaf(-h[r1], h[r1], 1.0f) * acc[nt][r1 + 8];
            unsigned hp = cvtpk(h[r0], h[r1]);
            unsigned tp = cvtpk(t0, t1);
            tbu[rv0 * TBS + col]        = (unsigned short)hp;
            tbu[rv1 * TBS + col]        = (unsigned short)(hp >> 16);
            tbu[(16 + rv0) * TBS + col] = (unsigned short)tp;
            tbu[(16 + rv1) * TBS + col] = (unsigned short)(tp >> 16);
        }
    }
}

// ---- one ODE f-eval: dz bf16 -> slab[sout]; returns div (all lanes) ----
__device__ __forceinline__ float feval(const float (&zs)[16], short8 e0, short8 e1,
                                       const char* __restrict__ ws, char* ring,
                                       short* tb, short* slabs, int sout,
                                       const floatx16& z16,
                                       const float (&bsc1)[4], const float (&bsc2)[4],
                                       const float (&bsc3)[4], float b4v,
                                       int lane, int m, int kq, int sw,
                                       int l31, int hi, int wave) {
    float* jb = (float*)tb;                       // overlays tb rows 0-8
    short* sl = slabs + sout * SLAB_SH;

    // layer-1 A: sw0 writes zs rows 0-15 (cvt_pk x8 -> two b128 stores);
    // sw1 writes eps rows 16-31. First VBAR publishes (no LBAR needed).
    if (sw == 0) {
        uint4 lo4 = { cvtpk(zs[0], zs[1]),  cvtpk(zs[2], zs[3]),
                      cvtpk(zs[4], zs[5]),  cvtpk(zs[6], zs[7]) };
        uint4 hi4 = { cvtpk(zs[8], zs[9]),  cvtpk(zs[10], zs[11]),
                      cvtpk(zs[12], zs[13]), cvtpk(zs[14], zs[15]) };
        *(uint4*)&tb[m * TBS + kq * 8]      = lo4;
        *(uint4*)&tb[m * TBS + 32 + kq * 8] = hi4;
    } else {
        *(short8*)&tb[(16 + m) * TBS + kq * 8]      = e0;
        *(short8*)&tb[(16 + m) * TBS + 32 + kq * 8] = e1;
    }

    floatx16 acc[4];

    gemm_segment<0, 4>(ws, ring, tb, acc, z16, lane, wave, sw, l31, hi);
    LBAR();                                         // tb reads done before overwrite
    transpose_acts(acc, tb, bsc1, sw, l31, hi);     // next VBAR publishes

    gemm_segment<4, 16>(ws, ring, tb, acc, z16, lane, wave, sw, l31, hi);
    LBAR();
    transpose_acts(acc, tb, bsc2, sw, l31, hi);

    gemm_segment<20, 16>(ws, ring, tb, acc, z16, lane, wave, sw, l31, hi);
    LBAR();
    transpose_acts(acc, tb, bsc3, sw, l31, hi);

    // ------------- layer 4: K=256, N=64 (wave: 32 cols), chunks 36-39 -------
    floatx16 a4;
#pragma unroll
    for (int c = 0; c < 4; c++) {
        const int G = 36 + c;
        const int gn = (G + 2 >= NCHUNK) ? G + 2 - NCHUNK : G + 2;  // cyclic
        stage_dma(ws, ring, gn, wave, lane);
        VBAR();
        const char* bp = ring + ((G & 3) * CHUNK);
        __builtin_amdgcn_s_setprio(1);
#pragma unroll
        for (int k4 = 0; k4 < 4; k4++) {
            short8 a = *(const short8*)&tb[l31 * TBS + (c * 4 + k4) * 16 + hi * 8];
            short8 b = *(const short8*)(bp + (k4 * 2 + sw) * 1024 + lane * 16);
            a4 = (c == 0 && k4 == 0) ? MFMA32(a, b, z16) : MFMA32(a, b, a4);
        }
        __builtin_amdgcn_s_setprio(0);
    }
    LBAR();                                          // tb A-reads done before jb

    // ---- epilogue: Jeps fp32 -> jb; dz = a4+b4 bf16 -> slab[sout] ----
#pragma unroll
    for (int p = 0; p < 4; p++) {
        const int r0 = 2 * p, r1 = r0 + 1;
        const int rv0 = (r0 & 3) + 8 * (r0 >> 2) + 4 * hi;
        const int rv1 = (r1 & 3) + 8 * (r1 >> 2) + 4 * hi;
        jb[rv0 * 68 + sw * 32 + l31] = a4[r0 + 8];
        jb[rv1 * 68 + sw * 32 + l31] = a4[r1 + 8];
        unsigned dp = cvtpk(a4[r0] + b4v, a4[r1] + b4v);
        ((unsigned short*)sl)[rv0 * SLAB_STR + sw * 32 + l31] = (unsigned short)dp;
        ((unsigned short*)sl)[rv1 * SLAB_STR + sw * 32 + l31] = (unsigned short)(dp >> 16);
    }
    LBAR();
    float div = 0.f;
#pragma unroll
    for (int q = 0; q < 2; q++) {
        floatx4 j0 = *(const floatx4*)&jb[m * 68 + kq * 8 + q * 4];
        floatx4 j1 = *(const floatx4*)&jb[m * 68 + 32 + kq * 8 + q * 4];
#pragma unroll
        for (int j = 0; j < 4; j++)
            div += j0[j] * bf2f(e0[q * 4 + j]) + j1[j] * bf2f(e1[q * 4 + j]);
    }
    div += __shfl_xor(div, 16, 64);
    div += __shfl_xor(div, 32, 64);
    LBAR();                             // jb dead before next feval's tb writes
    return div;
}

#define SLO(s) (*(const short8*)&slabs[(s) * SLAB_SH + m * SLAB_STR + kq * 8])
#define SHI(s) (*(const short8*)&slabs[(s) * SLAB_SH + m * SLAB_STR + 32 + kq * 8])

__global__ void __launch_bounds__(256, 2)
cnf_main(const float* __restrict__ x, const float* __restrict__ eps,
         const char* __restrict__ ws, float* __restrict__ out) {
    extern __shared__ char smem[];
    const int tid  = threadIdx.x;
    const int lane = tid & 63;
    const int wave = tid >> 6;
    const int group = wave >> 1, sw = wave & 1;
    const int m = lane & 15, kq = lane >> 4;
    const int l31 = lane & 31, hi = lane >> 5;
    char*  ring  = smem;
    short* tb    = (short*)(smem + RING_BYTES + group * GROUP_BYTES);
    short* slabs = (short*)(smem + RING_BYTES + group * GROUP_BYTES + TB_BYTES);
    const int row = blockIdx.x * 32 + group * 16 + m;

    float y[16];
    short8 e0, e1;
#pragma unroll
    for (int kt = 0; kt < 2; kt++)
#pragma unroll
        for (int q = 0; q < 2; q++) {
            floatx4 vx = *(const floatx4*)(x   + row * DIM + kt * 32 + kq * 8 + q * 4);
            floatx4 ve = *(const floatx4*)(eps + row * DIM + kt * 32 + kq * 8 + q * 4);
#pragma unroll
            for (int j = 0; j < 4; j++) y[kt * 8 + q * 4 + j] = vx[j];
            unsigned p0 = cvtpk(ve[0], ve[1]), p1 = cvtpk(ve[2], ve[3]);
            if (kt == 0) { e0[q*4+0]=(short)p0; e0[q*4+1]=(short)(p0>>16);
                           e0[q*4+2]=(short)p1; e0[q*4+3]=(short)(p1>>16); }
            else         { e1[q*4+0]=(short)p0; e1[q*4+1]=(short)(p0>>16);
                           e1[q*4+2]=(short)p1; e1[q*4+3]=(short)(p1>>16); }
        }

    // persistent zero accumulator (C operand of each segment's first MFMA)
    floatx16 z16;
#pragma unroll
    for (int i = 0; i < 16; i++) z16[i] = 0.0f;

    // per-lane bias registers: bsc = 2*log2(e)*b (folded into tanh arg)
    const float* bias = (const float*)(ws + BOFF);
    float bsc1[4], bsc2[4], bsc3[4];
#pragma unroll
    for (int nt = 0; nt < 4; nt++) {
        const int col = sw * 128 + nt * 32 + l31;
        bsc1[nt] = 2.885390082f * bias[col];
        bsc2[nt] = 2.885390082f * bias[256 + col];
        bsc3[nt] = 2.885390082f * bias[512 + col];
    }
    const float b4v = bias[768 + sw * 32 + l31];

    // zero both groups' slabs (0-coeff combines must not FMA NaN garbage)
    {
        short8 z = {0, 0, 0, 0, 0, 0, 0, 0};
#pragma unroll
        for (int g = 0; g < 2; g++) {
            short* sb = (short*)(smem + RING_BYTES + g * GROUP_BYTES + TB_BYTES);
            for (int k = tid; k < 432; k += 256) *(short8*)&sb[k * 8] = z;
        }
    }

    // prologue: DMA chunks 0,1 (depth-2 pipeline fill; first VBAR syncs it)
    stage_dma(ws, ring, 0, wave, lane);
    stage_dma(ws, ring, 1, wave, lane);

    float ylogp = 0.f;
    short8 zero8 = {0, 0, 0, 0, 0, 0, 0, 0};
    short8 k1a = zero8, k1b = zero8, k3a = zero8, k3b = zero8;

#pragma unroll 1
    for (int st = 0; st < 24; st++) {
        const int stage = st % 6;
        float c1, c2, c3, c4, c5, bw; int sout;
        switch (stage) {
            case 0: c1=0.f;           c2=0.f;            c3=0.f;           c4=0.f;            c5=0.f;            bw=0.022786458f;  sout=0; break;
            case 1: c1=0.05f;         c2=0.f;            c3=0.f;           c4=0.f;            c5=0.f;            bw=0.f;           sout=0; break;
            case 2: c1=0.01875f;      c2=0.05625f;       c3=0.f;           c4=0.f;            c5=0.f;            bw=0.112309075f;  sout=1; break;
            case 3: c1=0.244444444f;  c2=-0.933333333f;  c3=0.888888889f;  c4=0.f;            c5=0.f;            bw=0.162760417f;  sout=1; break;
            case 4: c1=0.738149672f;  c2=-2.898948331f;  c3=2.455723213f;  c4=-0.072702332f;  c5=0.f;            bw=-0.080593989f; sout=2; break;
            default:c1=0.711568813f;  c2=-2.689393939f;  c3=2.226605679f;  c4=0.069602273f;   c5=-0.068382826f;  bw=0.032738095f;  sout=0; break;
        }

        // zs = y + c1 k1(regs) + c2 slab0 + c3 k3(regs) + c4 slab1 + c5 slab2
        float zs[16];
        {
            short8 k2a = SLO(0), k2b = SHI(0);
            short8 k4a = SLO(1), k4b = SHI(1);
            short8 k5a = SLO(2), k5b = SHI(2);
#pragma unroll
            for (int j = 0; j < 8; j++) {
                zs[j]     = y[j]     + c1 * bf2f(k1a[j]) + c2 * bf2f(k2a[j])
                                     + c3 * bf2f(k3a[j]) + c4 * bf2f(k4a[j])
                                     + c5 * bf2f(k5a[j]);
                zs[8 + j] = y[8 + j] + c1 * bf2f(k1b[j]) + c2 * bf2f(k2b[j])
                                     + c3 * bf2f(k3b[j]) + c4 * bf2f(k4b[j])
                                     + c5 * bf2f(k5b[j]);
            }
        }

        const float d = feval(zs, e0, e1, ws, ring, tb, slabs, sout, z16,
                              bsc1, bsc2, bsc3, b4v,
                              lane, m, kq, sw, l31, hi, wave);

        if (stage == 0) { k1a = SLO(0); k1b = SHI(0); }   // k1 -> regs (slot 0 -> k2)
        if (stage == 2) { k3a = SLO(1); k3b = SHI(1); }   // k3 -> regs (slot 1 -> k4)
        if (stage == 5) {
            // y += b1 k1 + b3 k3 + b4 slab1 + b5 slab2 + b6 slab0
            short8 k4a = SLO(1), k4b = SHI(1);
            short8 k5a = SLO(2), k5b = SHI(2);
            short8 k6a = SLO(0), k6b = SHI(0);
#pragma unroll
            for (int j = 0; j < 8; j++) {
                y[j]     += 0.022786458f * bf2f(k1a[j]) + 0.112309075f * bf2f(k3a[j])
                          + 0.162760417f * bf2f(k4a[j]) - 0.080593989f * bf2f(k5a[j])
                          + 0.032738095f * bf2f(k6a[j]);
                y[8 + j] += 0.022786458f * bf2f(k1b[j]) + 0.112309075f * bf2f(k3b[j])
                          + 0.162760417f * bf2f(k4b[j]) - 0.080593989f * bf2f(k5b[j])
                          + 0.032738095f * bf2f(k6b[j]);
            }
        }
        ylogp -= bw * d;
    }

    float nrm = 0.f;
#pragma unroll
    for (int i = 0; i < 16; i++) nrm += y[i] * y[i];
    nrm += __shfl_xor(nrm, 16, 64);
    nrm += __shfl_xor(nrm, 32, 64);
    float res = -0.5f * nrm - LOG2PI_HALF_SUM - ylogp;
    asm volatile("s_waitcnt vmcnt(0)" ::: "memory");   // retire dangling prefetch
    if (sw == 0 && lane < 16) out[blockIdx.x * 32 + group * 16 + lane] = res;
}

// ---- weight pre-shuffle: fp32 [N][K] -> bf16 fragment-linear (32x32x16) ----
// frag = ktile*NT + ntile; lane l holds W[ntile*32 + (l&31)][ktile*16 + (l>>5)*8 + 0..7]
__global__ void prep_w(const float* __restrict__ W, short* __restrict__ outp,
                       int K, int NT, int KT) {
    int slot  = blockIdx.x * 256 + threadIdx.x;
    int total = KT * NT * 64;
    if (slot >= total) return;
    int lane  = slot & 63, frag = slot >> 6;
    int ntile = frag % NT, ktile = frag / NT;
    int n = ntile * 32 + (lane & 31);
    int k = ktile * 16 + (lane >> 5) * 8;
    short8 v;
#pragma unroll
    for (int j = 0; j < 8; j++) {
        union { float f; unsigned u; } w; w.f = W[n * K + k + j];
        unsigned r = w.u + 0x7FFFu + ((w.u >> 16) & 1u);
        v[j] = (short)(r >> 16);
    }
    *(short8*)(outp + slot * 8) = v;
}

__global__ void prep_b(const float* __restrict__ b1, const float* __restrict__ b2,
                       const float* __restrict__ b3, const float* __restrict__ b4,
                       float* __restrict__ dst) {
    int i = blockIdx.x * 256 + threadIdx.x;
    if (i < 256)      dst[i] = b1[i];
    else if (i < 512) dst[i] = b2[i - 256];
    else if (i < 768) dst[i] = b3[i - 512];
    else if (i < 832) dst[i] = b4[i - 768];
}

extern "C" void kernel_launch(void* const* d_in, const int* in_sizes, int n_in,
                              void* d_out, int out_size, void* d_ws, size_t ws_size,
                              hipStream_t stream) {
    const float* x   = (const float*)d_in[0];
    const float* eps = (const float*)d_in[1];
    const float* W1  = (const float*)d_in[2];
    const float* b1  = (const float*)d_in[3];
    const float* W2  = (const float*)d_in[4];
    const float* b2  = (const float*)d_in[5];
    const float* W3  = (const float*)d_in[6];
    const float* b3  = (const float*)d_in[7];
    const float* W4  = (const float*)d_in[8];
    const float* b4  = (const float*)d_in[9];
    char*  ws  = (char*)d_ws;
    float* out = (float*)d_out;

    static bool attr_set = false;
    if (!attr_set) {
        hipFuncSetAttribute(reinterpret_cast<const void*>(cnf_main),
                            hipFuncAttributeMaxDynamicSharedMemorySize, SMEM_BYTES);
        attr_set = true;
    }

    // W1: KT=4, NT=8  -> 32 frags  @ ws+0       (32KB,  chunks 0-3)
    // W2: KT=16,NT=8  -> 128 frags @ ws+32768   (128KB, chunks 4-19)
    // W3: KT=16,NT=8  -> 128 frags @ ws+163840  (128KB, chunks 20-35)
    // W4: KT=16,NT=2  -> 32 frags  @ ws+294912  (32KB,  chunks 36-39)
    prep_w<<<8,  256, 0, stream>>>(W1, (short*)(ws + 0),      64,  8, 4);
    prep_w<<<32, 256, 0, stream>>>(W2, (short*)(ws + 32768),  256, 8, 16);
    prep_w<<<32, 256, 0, stream>>>(W3, (short*)(ws + 163840), 256, 8, 16);
    prep_w<<<8,  256, 0, stream>>>(W4, (short*)(ws + 294912), 256, 2, 16);
    prep_b<<<4, 256, 0, stream>>>(b1, b2, b3, b4, (float*)(ws + BOFF));

    cnf_main<<<BATCH / 32, 256, SMEM_BYTES, stream>>>(x, eps, ws, out);
}

// Round 8
// 769.911 us; speedup vs baseline: 1.6202x; 1.6202x over previous
//
#include <hip/hip_runtime.h>

// ============================================================================
// CNF log-density, fused persistent kernel — v9: v7 + register-light VALU diet.
//   - v7 structure VERBATIM: DMA ring (4x8KB, global_load_lds, depth-2),
//     counted vmcnt(4) chunk barriers, N-split wave pairs, 32x32x16 val+tan
//     MFMA, bf16 k-slabs, flattened RK machine. (v7 = 774us, MfmaUtil 29.5%)
//   - NEW (reg-light only; v8's pipeline bank spilled -> L2 poison -> 1 GB
//     HBM restream):
//       * biases hoisted to 13 persistent VGPRs at kernel start (kills 16
//         latency-exposed global loads per feval)
//       * v_cvt_pk_bf16_f32 pairing for transpose / zs-pack / dz-pack
//         (manual 4-op RTNE -> 0.5 op/elem; hi halves via d16_hi stores)
// ============================================================================

#define DIM   64
#define HID   256
#define BATCH 32768
#define LOG2PI_HALF_SUM 58.8120661251f   // 32 * log(2*pi)

typedef float  floatx4  __attribute__((ext_vector_type(4)));
typedef float  floatx16 __attribute__((ext_vector_type(16)));
typedef short  short8   __attribute__((ext_vector_type(8)));

// ---- workspace: bf16 weights, fragment-linear, contiguous 40 x 8KB chunks --
// chunk c: W1 c0-3, W2 c4-19, W3 c20-35, W4 c36-39. frag = ktile*NT + ntile.
#define BOFF   327680    // biases fp32: b1[256] b2[256] b3[256] b4[64]
#define CHUNK  8192
#define NCHUNK 40

// ---- LDS ----
#define TBS         264              // shorts per tb row (256 + 8 pad)
#define TB_BYTES    16896            // 32 * 264 * 2
#define SLAB_STR    72               // shorts per slab row (64 + 8 pad)
#define SLAB_SH     1152             // shorts per slab (16*72)
#define RING_BYTES  32768            // 4 x 8KB chunk ring
#define GROUP_BYTES 23808            // tb + 3 slabs (16896 + 6912)
#define SMEM_BYTES  (RING_BYTES + 2 * GROUP_BYTES)   // 80384 -> 2 blocks/CU

#define MFMA32(a, b, c) __builtin_amdgcn_mfma_f32_32x32x16_bf16(a, b, c, 0, 0, 0)

// Chunk barrier: counted vmcnt (my 2 chunk-c loads done; 4 newer in flight),
// then raw barrier. NEVER vmcnt(0) in the main loop.
#define VBAR() do { asm volatile("s_waitcnt vmcnt(4)" ::: "memory"); \
    __builtin_amdgcn_s_barrier(); __builtin_amdgcn_sched_barrier(0); } while (0)
// DS-visibility barrier: does not touch vmcnt (keeps the count exact).
#define LBAR() do { asm volatile("s_waitcnt lgkmcnt(0)" ::: "memory"); \
    __builtin_amdgcn_s_barrier(); __builtin_amdgcn_sched_barrier(0); } while (0)

__device__ __forceinline__ unsigned cvtpk(float lo, float hi) {
    unsigned r;
    asm("v_cvt_pk_bf16_f32 %0, %1, %2" : "=v"(r) : "v"(lo), "v"(hi));
    return r;
}

__device__ __forceinline__ float bf2f(short s) {
    union { float f; unsigned u; } v;
    v.u = ((unsigned)(unsigned short)s) << 16;
    return v.f;
}

__device__ __forceinline__ float fast_tanh(float x) {
    float e = __expf(2.0f * x);
    return 1.0f - 2.0f * __builtin_amdgcn_rcpf(e + 1.0f);
}

// ---- async global->LDS: 16B/lane, LDS dest = wave-uniform base + lane*16 ----
__device__ __forceinline__ void gld_lds16(const char* g, char* l) {
    __builtin_amdgcn_global_load_lds(
        (const __attribute__((address_space(1))) void*)g,
        (__attribute__((address_space(3))) void*)l, 16, 0, 0);
}

// Stage chunk g into ring slot g%4: each wave DMAs its own 2KB slice (2 ops).
__device__ __forceinline__ void stage_dma(const char* __restrict__ ws, char* ring,
                                          int g, int wave, int lane) {
    const char* src = ws + g * CHUNK + wave * 2048 + lane * 16;
    char* dst = ring + (g & 3) * CHUNK + wave * 2048;
    gld_lds16(src, dst);
    gld_lds16(src + 1024, dst + 1024);
}

__device__ __forceinline__ floatx16 acc_init(float b) {
    floatx16 c;
#pragma unroll
    for (int r = 0; r < 8; r++) { c[r] = b; c[r + 8] = 0.f; }
    return c;
}

// acc (4 nt x 128 cols of this wave) -> tb rows 0-31 (h rows 0-15, t 16-31).
// Pairs (r, r+1): rv1 = rv0 + 1 (r even => (r&3) in {0,2}), so one cvt_pk
// feeds two rows; hi half lands via d16_hi store pattern.
__device__ __forceinline__ void transpose_acts(const floatx16 (&acc)[4], short* tb,
                                               int sw, int l31, int hi) {
    unsigned short* tbu = (unsigned short*)tb;
#pragma unroll
    for (int nt = 0; nt < 4; nt++) {
        const int col = sw * 128 + nt * 32 + l31;
#pragma unroll
        for (int p = 0; p < 4; p++) {
            const int r0 = 2 * p, r1 = r0 + 1;
            const int rv0 = (r0 & 3) + 8 * (r0 >> 2) + 4 * hi;
            const int rv1 = rv0 + 1;
            float h0 = fast_tanh(acc[nt][r0]);
            float h1 = fast_tanh(acc[nt][r1]);
            float t0 = __builtin_fmaf(-h0, h0, 1.0f) * acc[nt][r0 + 8];
            float t1 = __builtin_fmaf(-h1, h1, 1.0f) * acc[nt][r1 + 8];
            unsigned hp = cvtpk(h0, h1);
            unsigned tp = cvtpk(t0, t1);
            tbu[rv0 * TBS + col]        = (unsigned short)hp;
            tbu[rv1 * TBS + col]        = (unsigned short)(hp >> 16);
            tbu[(16 + rv0) * TBS + col] = (unsigned short)tp;
            tbu[(16 + rv1) * TBS + col] = (unsigned short)(tp >> 16);
        }
    }
}

// ---- one ODE f-eval: dz bf16 -> slab[sout]; returns div (all lanes) ----
__device__ __forceinline__ float feval(const float (&zs)[16], short8 e0, short8 e1,
                                       const char* __restrict__ ws, char* ring,
                                       short* tb, short* slabs, int sout,
                                       const float (&b1r)[4], const float (&b2r)[4],
                                       const float (&b3r)[4], float b4v,
                                       int lane, int m, int kq, int sw,
                                       int l31, int hi, int wave) {
    float* jb = (float*)tb;                       // overlays tb rows 0-8

    // layer-1 A: sw0 writes zs rows 0-15 (cvt_pk x8 -> two b128 stores);
    // sw1 writes eps rows 16-31.
    if (sw == 0) {
        uint4 lo4 = { cvtpk(zs[0], zs[1]),   cvtpk(zs[2], zs[3]),
                      cvtpk(zs[4], zs[5]),   cvtpk(zs[6], zs[7]) };
        uint4 hi4 = { cvtpk(zs[8], zs[9]),   cvtpk(zs[10], zs[11]),
                      cvtpk(zs[12], zs[13]), cvtpk(zs[14], zs[15]) };
        *(uint4*)&tb[m * TBS + kq * 8]      = lo4;
        *(uint4*)&tb[m * TBS + 32 + kq * 8] = hi4;
    } else {
        *(short8*)&tb[(16 + m) * TBS + kq * 8]      = e0;
        *(short8*)&tb[(16 + m) * TBS + 32 + kq * 8] = e1;
    }
    LBAR();

    floatx16 acc[4];

    // ---------------- layer 1: K=64, chunks 0-3 (kt = chunk) ----------------
#pragma unroll
    for (int nt = 0; nt < 4; nt++) acc[nt] = acc_init(b1r[nt]);
#pragma unroll
    for (int G = 0; G < 4; G++) {
        stage_dma(ws, ring, G + 2, wave, lane);
        VBAR();
        short8 a = *(const short8*)&tb[l31 * TBS + G * 16 + hi * 8];
        const char* bp = ring + (G & 3) * CHUNK;
        __builtin_amdgcn_s_setprio(1);
#pragma unroll
        for (int nt = 0; nt < 4; nt++) {
            short8 b = *(const short8*)(bp + (sw * 4 + nt) * 1024 + lane * 16);
            acc[nt] = MFMA32(a, b, acc[nt]);
        }
        __builtin_amdgcn_s_setprio(0);
    }
    LBAR();
    transpose_acts(acc, tb, sw, l31, hi);
    LBAR();

    // ---------------- layers 2,3: K=256, chunks 4-19 / 20-35 ----------------
#pragma unroll 1
    for (int layer = 0; layer < 2; layer++) {
        const int gb = 4 + layer * 16;
#pragma unroll
        for (int nt = 0; nt < 4; nt++)
            acc[nt] = acc_init(layer ? b3r[nt] : b2r[nt]);
#pragma unroll
        for (int c = 0; c < 16; c++) {
            const int G = gb + c;
            stage_dma(ws, ring, G + 2, wave, lane);      // max G+2 = 37, no wrap
            VBAR();
            short8 a = *(const short8*)&tb[l31 * TBS + c * 16 + hi * 8];
            const char* bp = ring + (G & 3) * CHUNK;
            __builtin_amdgcn_s_setprio(1);
#pragma unroll
            for (int nt = 0; nt < 4; nt++) {
                short8 b = *(const short8*)(bp + (sw * 4 + nt) * 1024 + lane * 16);
                acc[nt] = MFMA32(a, b, acc[nt]);
            }
            __builtin_amdgcn_s_setprio(0);
        }
        LBAR();
        transpose_acts(acc, tb, sw, l31, hi);
        LBAR();
    }

    // ------------- layer 4: K=256, N=64 (wave: 32 cols), chunks 36-39 -------
    floatx16 a4 = acc_init(b4v);
#pragma unroll
    for (int c = 0; c < 4; c++) {
        const int G = 36 + c;
        const int gn = (G + 2 >= NCHUNK) ? G + 2 - NCHUNK : G + 2;  // cyclic
        stage_dma(ws, ring, gn, wave, lane);
        VBAR();
        const char* bp = ring + (G & 3) * CHUNK;
        __builtin_amdgcn_s_setprio(1);
#pragma unroll
        for (int k4 = 0; k4 < 4; k4++) {
            short8 a = *(const short8*)&tb[l31 * TBS + (c * 4 + k4) * 16 + hi * 8];
            short8 b = *(const short8*)(bp + (k4 * 2 + sw) * 1024 + lane * 16);
            a4 = MFMA32(a, b, a4);
        }
        __builtin_amdgcn_s_setprio(0);
    }
    LBAR();

    // ---- epilogue: Jeps fp32 -> jb; dz bf16 (cvt_pk pairs) -> slab[sout] ----
    unsigned short* slu = (unsigned short*)(slabs + sout * SLAB_SH);
#pragma unroll
    for (int p = 0; p < 4; p++) {
        const int r0 = 2 * p, r1 = r0 + 1;
        const int rv0 = (r0 & 3) + 8 * (r0 >> 2) + 4 * hi;
        const int rv1 = rv0 + 1;
        jb[rv0 * 68 + sw * 32 + l31] = a4[r0 + 8];
        jb[rv1 * 68 + sw * 32 + l31] = a4[r1 + 8];
        unsigned dp = cvtpk(a4[r0], a4[r1]);
        slu[rv0 * SLAB_STR + sw * 32 + l31] = (unsigned short)dp;
        slu[rv1 * SLAB_STR + sw * 32 + l31] = (unsigned short)(dp >> 16);
    }
    LBAR();
    float div = 0.f;
#pragma unroll
    for (int q = 0; q < 2; q++) {
        floatx4 j0 = *(const floatx4*)&jb[m * 68 + kq * 8 + q * 4];
        floatx4 j1 = *(const floatx4*)&jb[m * 68 + 32 + kq * 8 + q * 4];
#pragma unroll
        for (int j = 0; j < 4; j++)
            div += j0[j] * bf2f(e0[q * 4 + j]) + j1[j] * bf2f(e1[q * 4 + j]);
    }
    div += __shfl_xor(div, 16, 64);
    div += __shfl_xor(div, 32, 64);
    LBAR();                             // jb dead before next feval's tb writes
    return div;
}

#define SLO(s) (*(const short8*)&slabs[(s) * SLAB_SH + m * SLAB_STR + kq * 8])
#define SHI(s) (*(const short8*)&slabs[(s) * SLAB_SH + m * SLAB_STR + 32 + kq * 8])

__global__ void __launch_bounds__(256, 2)
cnf_main(const float* __restrict__ x, const float* __restrict__ eps,
         const char* __restrict__ ws, float* __restrict__ out) {
    extern __shared__ char smem[];
    const int tid  = threadIdx.x;
    const int lane = tid & 63;
    const int wave = tid >> 6;
    const int group = wave >> 1, sw = wave & 1;
    const int m = lane & 15, kq = lane >> 4;
    const int l31 = lane & 31, hi = lane >> 5;
    char*  ring  = smem;
    short* tb    = (short*)(smem + RING_BYTES + group * GROUP_BYTES);
    short* slabs = (short*)(smem + RING_BYTES + group * GROUP_BYTES + TB_BYTES);
    const int row = blockIdx.x * 32 + group * 16 + m;

    float y[16];
    short8 e0, e1;
#pragma unroll
    for (int kt = 0; kt < 2; kt++)
#pragma unroll
        for (int q = 0; q < 2; q++) {
            floatx4 vx = *(const floatx4*)(x   + row * DIM + kt * 32 + kq * 8 + q * 4);
            floatx4 ve = *(const floatx4*)(eps + row * DIM + kt * 32 + kq * 8 + q * 4);
#pragma unroll
            for (int j = 0; j < 4; j++) y[kt * 8 + q * 4 + j] = vx[j];
            unsigned p0 = cvtpk(ve[0], ve[1]), p1 = cvtpk(ve[2], ve[3]);
            if (kt == 0) { e0[q*4+0]=(short)p0; e0[q*4+1]=(short)(p0>>16);
                           e0[q*4+2]=(short)p1; e0[q*4+3]=(short)(p1>>16); }
            else         { e1[q*4+0]=(short)p0; e1[q*4+1]=(short)(p0>>16);
                           e1[q*4+2]=(short)p1; e1[q*4+3]=(short)(p1>>16); }
        }

    // bias hoist: 13 persistent regs, kills 16 global loads per feval
    const float* bias = (const float*)(ws + BOFF);
    float b1r[4], b2r[4], b3r[4];
#pragma unroll
    for (int nt = 0; nt < 4; nt++) {
        const int col = sw * 128 + nt * 32 + l31;
        b1r[nt] = bias[col];
        b2r[nt] = bias[256 + col];
        b3r[nt] = bias[512 + col];
    }
    const float b4v = bias[768 + sw * 32 + l31];

    // zero both groups' slabs (0-coeff combines must not FMA NaN garbage)
    {
        short8 z = {0, 0, 0, 0, 0, 0, 0, 0};
#pragma unroll
        for (int g = 0; g < 2; g++) {
            short* sb = (short*)(smem + RING_BYTES + g * GROUP_BYTES + TB_BYTES);
            for (int k = tid; k < 432; k += 256) *(short8*)&sb[k * 8] = z;
        }
    }

    // prologue: DMA chunks 0,1 (depth-2 pipeline fill; first VBAR syncs it)
    stage_dma(ws, ring, 0, wave, lane);
    stage_dma(ws, ring, 1, wave, lane);

    float ylogp = 0.f;
    short8 zero8 = {0, 0, 0, 0, 0, 0, 0, 0};
    short8 k1a = zero8, k1b = zero8, k3a = zero8, k3b = zero8;

#pragma unroll 1
    for (int st = 0; st < 24; st++) {
        const int stage = st % 6;
        float c1, c2, c3, c4, c5, bw; int sout;
        switch (stage) {
            case 0: c1=0.f;           c2=0.f;            c3=0.f;           c4=0.f;            c5=0.f;            bw=0.022786458f;  sout=0; break;
            case 1: c1=0.05f;         c2=0.f;            c3=0.f;           c4=0.f;            c5=0.f;            bw=0.f;           sout=0; break;
            case 2: c1=0.01875f;      c2=0.05625f;       c3=0.f;           c4=0.f;            c5=0.f;            bw=0.112309075f;  sout=1; break;
            case 3: c1=0.244444444f;  c2=-0.933333333f;  c3=0.888888889f;  c4=0.f;            c5=0.f;            bw=0.162760417f;  sout=1; break;
            case 4: c1=0.738149672f;  c2=-2.898948331f;  c3=2.455723213f;  c4=-0.072702332f;  c5=0.f;            bw=-0.080593989f; sout=2; break;
            default:c1=0.711568813f;  c2=-2.689393939f;  c3=2.226605679f;  c4=0.069602273f;   c5=-0.068382826f;  bw=0.032738095f;  sout=0; break;
        }

        // zs = y + c1 k1(regs) + c2 slab0 + c3 k3(regs) + c4 slab1 + c5 slab2
        float zs[16];
        {
            short8 k2a = SLO(0), k2b = SHI(0);
            short8 k4a = SLO(1), k4b = SHI(1);
            short8 k5a = SLO(2), k5b = SHI(2);
#pragma unroll
            for (int j = 0; j < 8; j++) {
                zs[j]     = y[j]     + c1 * bf2f(k1a[j]) + c2 * bf2f(k2a[j])
                                     + c3 * bf2f(k3a[j]) + c4 * bf2f(k4a[j])
                                     + c5 * bf2f(k5a[j]);
                zs[8 + j] = y[8 + j] + c1 * bf2f(k1b[j]) + c2 * bf2f(k2b[j])
                                     + c3 * bf2f(k3b[j]) + c4 * bf2f(k4b[j])
                                     + c5 * bf2f(k5b[j]);
            }
        }

        const float d = feval(zs, e0, e1, ws, ring, tb, slabs, sout,
                              b1r, b2r, b3r, b4v,
                              lane, m, kq, sw, l31, hi, wave);

        if (stage == 0) { k1a = SLO(0); k1b = SHI(0); }   // k1 -> regs (slot 0 -> k2)
        if (stage == 2) { k3a = SLO(1); k3b = SHI(1); }   // k3 -> regs (slot 1 -> k4)
        if (stage == 5) {
            // y += b1 k1 + b3 k3 + b4 slab1 + b5 slab2 + b6 slab0
            short8 k4a = SLO(1), k4b = SHI(1);
            short8 k5a = SLO(2), k5b = SHI(2);
            short8 k6a = SLO(0), k6b = SHI(0);
#pragma unroll
            for (int j = 0; j < 8; j++) {
                y[j]     += 0.022786458f * bf2f(k1a[j]) + 0.112309075f * bf2f(k3a[j])
                          + 0.162760417f * bf2f(k4a[j]) - 0.080593989f * bf2f(k5a[j])
                          + 0.032738095f * bf2f(k6a[j]);
                y[8 + j] += 0.022786458f * bf2f(k1b[j]) + 0.112309075f * bf2f(k3b[j])
                          + 0.162760417f * bf2f(k4b[j]) - 0.080593989f * bf2f(k5b[j])
                          + 0.032738095f * bf2f(k6b[j]);
            }
        }
        ylogp -= bw * d;
    }

    float nrm = 0.f;
#pragma unroll
    for (int i = 0; i < 16; i++) nrm += y[i] * y[i];
    nrm += __shfl_xor(nrm, 16, 64);
    nrm += __shfl_xor(nrm, 32, 64);
    float res = -0.5f * nrm - LOG2PI_HALF_SUM - ylogp;
    asm volatile("s_waitcnt vmcnt(0)" ::: "memory");   // retire dangling prefetch
    if (sw == 0 && lane < 16) out[blockIdx.x * 32 + group * 16 + lane] = res;
}

// ---- weight pre-shuffle: fp32 [N][K] -> bf16 fragment-linear (32x32x16) ----
// frag = ktile*NT + ntile; lane l holds W[ntile*32 + (l&31)][ktile*16 + (l>>5)*8 + 0..7]
__global__ void prep_w(const float* __restrict__ W, short* __restrict__ outp,
                       int K, int NT, int KT) {
    int slot  = blockIdx.x * 256 + threadIdx.x;
    int total = KT * NT * 64;
    if (slot >= total) return;
    int lane  = slot & 63, frag = slot >> 6;
    int ntile = frag % NT, ktile = frag / NT;
    int n = ntile * 32 + (lane & 31);
    int k = ktile * 16 + (lane >> 5) * 8;
    short8 v;
#pragma unroll
    for (int j = 0; j < 8; j++) {
        union { float f; unsigned u; } w; w.f = W[n * K + k + j];
        unsigned r = w.u + 0x7FFFu + ((w.u >> 16) & 1u);
        v[j] = (short)(r >> 16);
    }
    *(short8*)(outp + slot * 8) = v;
}

__global__ void prep_b(const float* __restrict__ b1, const float* __restrict__ b2,
                       const float* __restrict__ b3, const float* __restrict__ b4,
                       float* __restrict__ dst) {
    int i = blockIdx.x * 256 + threadIdx.x;
    if (i < 256)      dst[i] = b1[i];
    else if (i < 512) dst[i] = b2[i - 256];
    else if (i < 768) dst[i] = b3[i - 512];
    else if (i < 832) dst[i] = b4[i - 768];
}

extern "C" void kernel_launch(void* const* d_in, const int* in_sizes, int n_in,
                              void* d_out, int out_size, void* d_ws, size_t ws_size,
                              hipStream_t stream) {
    const float* x   = (const float*)d_in[0];
    const float* eps = (const float*)d_in[1];
    const float* W1  = (const float*)d_in[2];
    const float* b1  = (const float*)d_in[3];
    const float* W2  = (const float*)d_in[4];
    const float* b2  = (const float*)d_in[5];
    const float* W3  = (const float*)d_in[6];
    const float* b3  = (const float*)d_in[7];
    const float* W4  = (const float*)d_in[8];
    const float* b4  = (const float*)d_in[9];
    char*  ws  = (char*)d_ws;
    float* out = (float*)d_out;

    static bool attr_set = false;
    if (!attr_set) {
        hipFuncSetAttribute(reinterpret_cast<const void*>(cnf_main),
                            hipFuncAttributeMaxDynamicSharedMemorySize, SMEM_BYTES);
        attr_set = true;
    }

    // W1: KT=4, NT=8  -> 32 frags  @ ws+0       (32KB,  chunks 0-3)
    // W2: KT=16,NT=8  -> 128 frags @ ws+32768   (128KB, chunks 4-19)
    // W3: KT=16,NT=8  -> 128 frags @ ws+163840  (128KB, chunks 20-35)
    // W4: KT=16,NT=2  -> 32 frags  @ ws+294912  (32KB,  chunks 36-39)
    prep_w<<<8,  256, 0, stream>>>(W1, (short*)(ws + 0),      64,  8, 4);
    prep_w<<<32, 256, 0, stream>>>(W2, (short*)(ws + 32768),  256, 8, 16);
    prep_w<<<32, 256, 0, stream>>>(W3, (short*)(ws + 163840), 256, 8, 16);
    prep_w<<<8,  256, 0, stream>>>(W4, (short*)(ws + 294912), 256, 2, 16);
    prep_b<<<4, 256, 0, stream>>>(b1, b2, b3, b4, (float*)(ws + BOFF));

    cnf_main<<<BATCH / 32, 256, SMEM_BYTES, stream>>>(x, eps, ws, out);
}

// Round 9
// 732.220 us; speedup vs baseline: 1.7036x; 1.0515x over previous
//
#include <hip/hip_runtime.h>

// ============================================================================
// CNF log-density, fused persistent kernel — v10: deep phases, 8-wave block.
//   - Per-wave datapath identical to v9 (32x32x16 val+tan MFMA, N-split wave
//     pairs, bf16 k-slabs, flattened RK, cvt_pk diet, bias hoist). v9 = 770us.
//   - Geometry: block = 512 thr = 8 waves = 4 row-groups, ONE block/CU (same
//     2 waves/SIMD), ring = 8 x 8KB slots. Chunks processed in 4-CHUNK PHASES:
//     VBAR -> stage 4 chunks (1 DMA op/wave) -> 16 MFMAs + 20 ds_reads.
//     Barriers/feval: 50 -> 20; MFMA pipe-cycles per barrier: 128 -> 512.
//   - vmcnt(0) per phase is exact: only the 4 chunks staged last phase are
//     outstanding, aged a full phase (>=600cy >> L2 ~200cy) -> wait ~0.
//     Stage-after-barrier makes ring-slot reuse provably race-free.
//   - LDS 160768B = 64KB ring + 4 x 23808 group (tb + 3 slabs). 3KB spare.
// ============================================================================

#define DIM   64
#define HID   256
#define BATCH 32768
#define LOG2PI_HALF_SUM 58.8120661251f   // 32 * log(2*pi)

typedef float  floatx4  __attribute__((ext_vector_type(4)));
typedef float  floatx16 __attribute__((ext_vector_type(16)));
typedef short  short8   __attribute__((ext_vector_type(8)));

// ---- workspace: bf16 weights, fragment-linear, contiguous 40 x 8KB chunks --
// chunk c: W1 c0-3, W2 c4-19, W3 c20-35, W4 c36-39. frag = ktile*NT + ntile.
#define BOFF   327680    // biases fp32: b1[256] b2[256] b3[256] b4[64]
#define CHUNK  8192
#define NCHUNK 40

// ---- LDS ----
#define TBS         264              // shorts per tb row (256 + 8 pad)
#define TB_BYTES    16896            // 32 * 264 * 2
#define SLAB_STR    72               // shorts per slab row (64 + 8 pad)
#define SLAB_SH     1152             // shorts per slab (16*72)
#define RING_BYTES  65536            // 8 x 8KB chunk ring
#define GROUP_BYTES 23808            // tb + 3 slabs (16896 + 6912)
#define SMEM_BYTES  (RING_BYTES + 4 * GROUP_BYTES)   // 160768 -> 1 block/CU

#define MFMA32(a, b, c) __builtin_amdgcn_mfma_f32_32x32x16_bf16(a, b, c, 0, 0, 0)

// Phase barrier: the only outstanding VMEM ops are the 4 chunks staged last
// phase (aged one full compute phase) -> vmcnt(0) is exact, not a drain.
#define VBAR() do { asm volatile("s_waitcnt vmcnt(0)" ::: "memory"); \
    __builtin_amdgcn_s_barrier(); __builtin_amdgcn_sched_barrier(0); } while (0)
// DS-visibility barrier: does not touch vmcnt (stage chain stays in flight).
#define LBAR() do { asm volatile("s_waitcnt lgkmcnt(0)" ::: "memory"); \
    __builtin_amdgcn_s_barrier(); __builtin_amdgcn_sched_barrier(0); } while (0)

__device__ __forceinline__ unsigned cvtpk(float lo, float hi) {
    unsigned r;
    asm("v_cvt_pk_bf16_f32 %0, %1, %2" : "=v"(r) : "v"(lo), "v"(hi));
    return r;
}

__device__ __forceinline__ float bf2f(short s) {
    union { float f; unsigned u; } v;
    v.u = ((unsigned)(unsigned short)s) << 16;
    return v.f;
}

__device__ __forceinline__ float fast_tanh(float x) {
    float e = __expf(2.0f * x);
    return 1.0f - 2.0f * __builtin_amdgcn_rcpf(e + 1.0f);
}

// ---- async global->LDS: 16B/lane, LDS dest = wave-uniform base + lane*16 ----
__device__ __forceinline__ void gld_lds16(const char* g, char* l) {
    __builtin_amdgcn_global_load_lds(
        (const __attribute__((address_space(1))) void*)g,
        (__attribute__((address_space(3))) void*)l, 16, 0, 0);
}

// Stage chunk g into ring slot g%8: each of 8 waves DMAs its 1KB slice (1 op).
__device__ __forceinline__ void stage_dma(const char* __restrict__ ws, char* ring,
                                          int g, int wave, int lane) {
    const char* src = ws + g * CHUNK + wave * 1024 + lane * 16;
    char* dst = ring + (g & 7) * CHUNK + wave * 1024;
    gld_lds16(src, dst);
}

__device__ __forceinline__ floatx16 acc_init(float b) {
    floatx16 c;
#pragma unroll
    for (int r = 0; r < 8; r++) { c[r] = b; c[r + 8] = 0.f; }
    return c;
}

// acc (4 nt x 128 cols of this wave) -> tb rows 0-31 (h rows 0-15, t 16-31).
__device__ __forceinline__ void transpose_acts(const floatx16 (&acc)[4], short* tb,
                                               int sw, int l31, int hi) {
    unsigned short* tbu = (unsigned short*)tb;
#pragma unroll
    for (int nt = 0; nt < 4; nt++) {
        const int col = sw * 128 + nt * 32 + l31;
#pragma unroll
        for (int p = 0; p < 4; p++) {
            const int r0 = 2 * p, r1 = r0 + 1;
            const int rv0 = (r0 & 3) + 8 * (r0 >> 2) + 4 * hi;
            const int rv1 = rv0 + 1;
            float h0 = fast_tanh(acc[nt][r0]);
            float h1 = fast_tanh(acc[nt][r1]);
            float t0 = __builtin_fmaf(-h0, h0, 1.0f) * acc[nt][r0 + 8];
            float t1 = __builtin_fmaf(-h1, h1, 1.0f) * acc[nt][r1 + 8];
            unsigned hp = cvtpk(h0, h1);
            unsigned tp = cvtpk(t0, t1);
            tbu[rv0 * TBS + col]        = (unsigned short)hp;
            tbu[rv1 * TBS + col]        = (unsigned short)(hp >> 16);
            tbu[(16 + rv0) * TBS + col] = (unsigned short)tp;
            tbu[(16 + rv1) * TBS + col] = (unsigned short)(tp >> 16);
        }
    }
}

// ---- one ODE f-eval: dz bf16 -> slab[sout]; returns div (all lanes) ----
__device__ __forceinline__ float feval(const float (&zs)[16], short8 e0, short8 e1,
                                       const char* __restrict__ ws, char* ring,
                                       short* tb, short* slabs, int sout,
                                       const float (&b1r)[4], const float (&b2r)[4],
                                       const float (&b3r)[4], float b4v,
                                       int lane, int m, int kq, int sw,
                                       int l31, int hi, int wave) {
    float* jb = (float*)tb;                       // overlays tb rows 0-8

    // layer-1 A: sw0 writes zs rows 0-15; sw1 writes eps rows 16-31.
    if (sw == 0) {
        uint4 lo4 = { cvtpk(zs[0], zs[1]),   cvtpk(zs[2], zs[3]),
                      cvtpk(zs[4], zs[5]),   cvtpk(zs[6], zs[7]) };
        uint4 hi4 = { cvtpk(zs[8], zs[9]),   cvtpk(zs[10], zs[11]),
                      cvtpk(zs[12], zs[13]), cvtpk(zs[14], zs[15]) };
        *(uint4*)&tb[m * TBS + kq * 8]      = lo4;
        *(uint4*)&tb[m * TBS + 32 + kq * 8] = hi4;
    } else {
        *(short8*)&tb[(16 + m) * TBS + kq * 8]      = e0;
        *(short8*)&tb[(16 + m) * TBS + 32 + kq * 8] = e1;
    }
    LBAR();

    floatx16 acc[4];

    // ---------- layer 1 (one phase): read chunks 0-3, stage 4-7 ----------
#pragma unroll
    for (int nt = 0; nt < 4; nt++) acc[nt] = acc_init(b1r[nt]);
    VBAR();
#pragma unroll
    for (int s = 0; s < 4; s++) stage_dma(ws, ring, 4 + s, wave, lane);
#pragma unroll
    for (int G = 0; G < 4; G++) {
        short8 a = *(const short8*)&tb[l31 * TBS + G * 16 + hi * 8];
        const char* bp = ring + (G & 7) * CHUNK;
        __builtin_amdgcn_s_setprio(1);
#pragma unroll
        for (int nt = 0; nt < 4; nt++) {
            short8 b = *(const short8*)(bp + (sw * 4 + nt) * 1024 + lane * 16);
            acc[nt] = MFMA32(a, b, acc[nt]);
        }
        __builtin_amdgcn_s_setprio(0);
    }
    LBAR();
    transpose_acts(acc, tb, sw, l31, hi);
    LBAR();

    // ---------- layers 2,3: 4 phases each (chunks 4-19 / 20-35) ----------
#pragma unroll 1
    for (int layer = 0; layer < 2; layer++) {
        const int gb = 4 + layer * 16;
#pragma unroll
        for (int nt = 0; nt < 4; nt++)
            acc[nt] = acc_init(layer ? b3r[nt] : b2r[nt]);
#pragma unroll
        for (int pp = 0; pp < 4; pp++) {
            const int c0 = gb + pp * 4;
            VBAR();
#pragma unroll
            for (int s = 0; s < 4; s++) stage_dma(ws, ring, c0 + 4 + s, wave, lane);
#pragma unroll
            for (int cc = 0; cc < 4; cc++) {
                const int kt = pp * 4 + cc;
                short8 a = *(const short8*)&tb[l31 * TBS + kt * 16 + hi * 8];
                const char* bp = ring + ((c0 + cc) & 7) * CHUNK;
                __builtin_amdgcn_s_setprio(1);
#pragma unroll
                for (int nt = 0; nt < 4; nt++) {
                    short8 b = *(const short8*)(bp + (sw * 4 + nt) * 1024 + lane * 16);
                    acc[nt] = MFMA32(a, b, acc[nt]);
                }
                __builtin_amdgcn_s_setprio(0);
            }
        }
        LBAR();
        transpose_acts(acc, tb, sw, l31, hi);
        LBAR();
    }

    // ---------- layer 4 (one phase): read 36-39, stage 0-3 (next feval) ----
    floatx16 a4 = acc_init(b4v);
    VBAR();
#pragma unroll
    for (int s = 0; s < 4; s++) stage_dma(ws, ring, s, wave, lane);
#pragma unroll
    for (int c = 0; c < 4; c++) {
        const char* bp = ring + ((36 + c) & 7) * CHUNK;
        __builtin_amdgcn_s_setprio(1);
#pragma unroll
        for (int k4 = 0; k4 < 4; k4++) {
            short8 a = *(const short8*)&tb[l31 * TBS + (c * 4 + k4) * 16 + hi * 8];
            short8 b = *(const short8*)(bp + (k4 * 2 + sw) * 1024 + lane * 16);
            a4 = MFMA32(a, b, a4);
        }
        __builtin_amdgcn_s_setprio(0);
    }
    LBAR();

    // ---- epilogue: Jeps fp32 -> jb; dz bf16 (cvt_pk pairs) -> slab[sout] ----
    unsigned short* slu = (unsigned short*)(slabs + sout * SLAB_SH);
#pragma unroll
    for (int p = 0; p < 4; p++) {
        const int r0 = 2 * p, r1 = r0 + 1;
        const int rv0 = (r0 & 3) + 8 * (r0 >> 2) + 4 * hi;
        const int rv1 = rv0 + 1;
        jb[rv0 * 68 + sw * 32 + l31] = a4[r0 + 8];
        jb[rv1 * 68 + sw * 32 + l31] = a4[r1 + 8];
        unsigned dp = cvtpk(a4[r0], a4[r1]);
        slu[rv0 * SLAB_STR + sw * 32 + l31] = (unsigned short)dp;
        slu[rv1 * SLAB_STR + sw * 32 + l31] = (unsigned short)(dp >> 16);
    }
    LBAR();
    float div = 0.f;
#pragma unroll
    for (int q = 0; q < 2; q++) {
        floatx4 j0 = *(const floatx4*)&jb[m * 68 + kq * 8 + q * 4];
        floatx4 j1 = *(const floatx4*)&jb[m * 68 + 32 + kq * 8 + q * 4];
#pragma unroll
        for (int j = 0; j < 4; j++)
            div += j0[j] * bf2f(e0[q * 4 + j]) + j1[j] * bf2f(e1[q * 4 + j]);
    }
    div += __shfl_xor(div, 16, 64);
    div += __shfl_xor(div, 32, 64);
    LBAR();                             // jb dead before next feval's tb writes
    return div;
}

#define SLO(s) (*(const short8*)&slabs[(s) * SLAB_SH + m * SLAB_STR + kq * 8])
#define SHI(s) (*(const short8*)&slabs[(s) * SLAB_SH + m * SLAB_STR + 32 + kq * 8])

__global__ void __launch_bounds__(512, 2)
cnf_main(const float* __restrict__ x, const float* __restrict__ eps,
         const char* __restrict__ ws, float* __restrict__ out) {
    extern __shared__ char smem[];
    const int tid  = threadIdx.x;
    const int lane = tid & 63;
    const int wave = tid >> 6;
    const int group = wave >> 1, sw = wave & 1;
    const int m = lane & 15, kq = lane >> 4;
    const int l31 = lane & 31, hi = lane >> 5;
    char*  ring  = smem;
    short* tb    = (short*)(smem + RING_BYTES + group * GROUP_BYTES);
    short* slabs = (short*)(smem + RING_BYTES + group * GROUP_BYTES + TB_BYTES);
    const int row = blockIdx.x * 64 + group * 16 + m;

    float y[16];
    short8 e0, e1;
#pragma unroll
    for (int kt = 0; kt < 2; kt++)
#pragma unroll
        for (int q = 0; q < 2; q++) {
            floatx4 vx = *(const floatx4*)(x   + row * DIM + kt * 32 + kq * 8 + q * 4);
            floatx4 ve = *(const floatx4*)(eps + row * DIM + kt * 32 + kq * 8 + q * 4);
#pragma unroll
            for (int j = 0; j < 4; j++) y[kt * 8 + q * 4 + j] = vx[j];
            unsigned p0 = cvtpk(ve[0], ve[1]), p1 = cvtpk(ve[2], ve[3]);
            if (kt == 0) { e0[q*4+0]=(short)p0; e0[q*4+1]=(short)(p0>>16);
                           e0[q*4+2]=(short)p1; e0[q*4+3]=(short)(p1>>16); }
            else         { e1[q*4+0]=(short)p0; e1[q*4+1]=(short)(p0>>16);
                           e1[q*4+2]=(short)p1; e1[q*4+3]=(short)(p1>>16); }
        }

    // bias hoist: 13 persistent regs, kills 16 global loads per feval
    const float* bias = (const float*)(ws + BOFF);
    float b1r[4], b2r[4], b3r[4];
#pragma unroll
    for (int nt = 0; nt < 4; nt++) {
        const int col = sw * 128 + nt * 32 + l31;
        b1r[nt] = bias[col];
        b2r[nt] = bias[256 + col];
        b3r[nt] = bias[512 + col];
    }
    const float b4v = bias[768 + sw * 32 + l31];

    // zero all groups' slabs (0-coeff combines must not FMA NaN garbage)
    {
        short8 z = {0, 0, 0, 0, 0, 0, 0, 0};
#pragma unroll
        for (int g = 0; g < 4; g++) {
            short* sb = (short*)(smem + RING_BYTES + g * GROUP_BYTES + TB_BYTES);
            for (int k = tid; k < 432; k += 512) *(short8*)&sb[k * 8] = z;
        }
    }

    // prologue: stage chunks 0-3 (first feval's layer-1 VBAR syncs them)
#pragma unroll
    for (int s = 0; s < 4; s++) stage_dma(ws, ring, s, wave, lane);

    float ylogp = 0.f;
    short8 zero8 = {0, 0, 0, 0, 0, 0, 0, 0};
    short8 k1a = zero8, k1b = zero8, k3a = zero8, k3b = zero8;

#pragma unroll 1
    for (int st = 0; st < 24; st++) {
        const int stage = st % 6;
        float c1, c2, c3, c4, c5, bw; int sout;
        switch (stage) {
            case 0: c1=0.f;           c2=0.f;            c3=0.f;           c4=0.f;            c5=0.f;            bw=0.022786458f;  sout=0; break;
            case 1: c1=0.05f;         c2=0.f;            c3=0.f;           c4=0.f;            c5=0.f;            bw=0.f;           sout=0; break;
            case 2: c1=0.01875f;      c2=0.05625f;       c3=0.f;           c4=0.f;            c5=0.f;            bw=0.112309075f;  sout=1; break;
            case 3: c1=0.244444444f;  c2=-0.933333333f;  c3=0.888888889f;  c4=0.f;            c5=0.f;            bw=0.162760417f;  sout=1; break;
            case 4: c1=0.738149672f;  c2=-2.898948331f;  c3=2.455723213f;  c4=-0.072702332f;  c5=0.f;            bw=-0.080593989f; sout=2; break;
            default:c1=0.711568813f;  c2=-2.689393939f;  c3=2.226605679f;  c4=0.069602273f;   c5=-0.068382826f;  bw=0.032738095f;  sout=0; break;
        }

        // zs = y + c1 k1(regs) + c2 slab0 + c3 k3(regs) + c4 slab1 + c5 slab2
        float zs[16];
        {
            short8 k2a = SLO(0), k2b = SHI(0);
            short8 k4a = SLO(1), k4b = SHI(1);
            short8 k5a = SLO(2), k5b = SHI(2);
#pragma unroll
            for (int j = 0; j < 8; j++) {
                zs[j]     = y[j]     + c1 * bf2f(k1a[j]) + c2 * bf2f(k2a[j])
                                     + c3 * bf2f(k3a[j]) + c4 * bf2f(k4a[j])
                                     + c5 * bf2f(k5a[j]);
                zs[8 + j] = y[8 + j] + c1 * bf2f(k1b[j]) + c2 * bf2f(k2b[j])
                                     + c3 * bf2f(k3b[j]) + c4 * bf2f(k4b[j])
                                     + c5 * bf2f(k5b[j]);
            }
        }

        const float d = feval(zs, e0, e1, ws, ring, tb, slabs, sout,
                              b1r, b2r, b3r, b4v,
                              lane, m, kq, sw, l31, hi, wave);

        if (stage == 0) { k1a = SLO(0); k1b = SHI(0); }   // k1 -> regs (slot 0 -> k2)
        if (stage == 2) { k3a = SLO(1); k3b = SHI(1); }   // k3 -> regs (slot 1 -> k4)
        if (stage == 5) {
            // y += b1 k1 + b3 k3 + b4 slab1 + b5 slab2 + b6 slab0
            short8 k4a = SLO(1), k4b = SHI(1);
            short8 k5a = SLO(2), k5b = SHI(2);
            short8 k6a = SLO(0), k6b = SHI(0);
#pragma unroll
            for (int j = 0; j < 8; j++) {
                y[j]     += 0.022786458f * bf2f(k1a[j]) + 0.112309075f * bf2f(k3a[j])
                          + 0.162760417f * bf2f(k4a[j]) - 0.080593989f * bf2f(k5a[j])
                          + 0.032738095f * bf2f(k6a[j]);
                y[8 + j] += 0.022786458f * bf2f(k1b[j]) + 0.112309075f * bf2f(k3b[j])
                          + 0.162760417f * bf2f(k4b[j]) - 0.080593989f * bf2f(k5b[j])
                          + 0.032738095f * bf2f(k6b[j]);
            }
        }
        ylogp -= bw * d;
    }

    float nrm = 0.f;
#pragma unroll
    for (int i = 0; i < 16; i++) nrm += y[i] * y[i];
    nrm += __shfl_xor(nrm, 16, 64);
    nrm += __shfl_xor(nrm, 32, 64);
    float res = -0.5f * nrm - LOG2PI_HALF_SUM - ylogp;
    asm volatile("s_waitcnt vmcnt(0)" ::: "memory");   // retire dangling prefetch
    if (sw == 0 && lane < 16) out[blockIdx.x * 64 + group * 16 + lane] = res;
}

// ---- weight pre-shuffle: fp32 [N][K] -> bf16 fragment-linear (32x32x16) ----
// frag = ktile*NT + ntile; lane l holds W[ntile*32 + (l&31)][ktile*16 + (l>>5)*8 + 0..7]
__global__ void prep_w(const float* __restrict__ W, short* __restrict__ outp,
                       int K, int NT, int KT) {
    int slot  = blockIdx.x * 256 + threadIdx.x;
    int total = KT * NT * 64;
    if (slot >= total) return;
    int lane  = slot & 63, frag = slot >> 6;
    int ntile = frag % NT, ktile = frag / NT;
    int n = ntile * 32 + (lane & 31);
    int k = ktile * 16 + (lane >> 5) * 8;
    short8 v;
#pragma unroll
    for (int j = 0; j < 8; j++) {
        union { float f; unsigned u; } w; w.f = W[n * K + k + j];
        unsigned r = w.u + 0x7FFFu + ((w.u >> 16) & 1u);
        v[j] = (short)(r >> 16);
    }
    *(short8*)(outp + slot * 8) = v;
}

__global__ void prep_b(const float* __restrict__ b1, const float* __restrict__ b2,
                       const float* __restrict__ b3, const float* __restrict__ b4,
                       float* __restrict__ dst) {
    int i = blockIdx.x * 256 + threadIdx.x;
    if (i < 256)      dst[i] = b1[i];
    else if (i < 512) dst[i] = b2[i - 256];
    else if (i < 768) dst[i] = b3[i - 512];
    else if (i < 832) dst[i] = b4[i - 768];
}

extern "C" void kernel_launch(void* const* d_in, const int* in_sizes, int n_in,
                              void* d_out, int out_size, void* d_ws, size_t ws_size,
                              hipStream_t stream) {
    const float* x   = (const float*)d_in[0];
    const float* eps = (const float*)d_in[1];
    const float* W1  = (const float*)d_in[2];
    const float* b1  = (const float*)d_in[3];
    const float* W2  = (const float*)d_in[4];
    const float* b2  = (const float*)d_in[5];
    const float* W3  = (const float*)d_in[6];
    const float* b3  = (const float*)d_in[7];
    const float* W4  = (const float*)d_in[8];
    const float* b4  = (const float*)d_in[9];
    char*  ws  = (char*)d_ws;
    float* out = (float*)d_out;

    static bool attr_set = false;
    if (!attr_set) {
        hipFuncSetAttribute(reinterpret_cast<const void*>(cnf_main),
                            hipFuncAttributeMaxDynamicSharedMemorySize, SMEM_BYTES);
        attr_set = true;
    }

    // W1: KT=4, NT=8  -> 32 frags  @ ws+0       (32KB,  chunks 0-3)
    // W2: KT=16,NT=8  -> 128 frags @ ws+32768   (128KB, chunks 4-19)
    // W3: KT=16,NT=8  -> 128 frags @ ws+163840  (128KB, chunks 20-35)
    // W4: KT=16,NT=2  -> 32 frags  @ ws+294912  (32KB,  chunks 36-39)
    prep_w<<<8,  256, 0, stream>>>(W1, (short*)(ws + 0),      64,  8, 4);
    prep_w<<<32, 256, 0, stream>>>(W2, (short*)(ws + 32768),  256, 8, 16);
    prep_w<<<32, 256, 0, stream>>>(W3, (short*)(ws + 163840), 256, 8, 16);
    prep_w<<<8,  256, 0, stream>>>(W4, (short*)(ws + 294912), 256, 2, 16);
    prep_b<<<4, 256, 0, stream>>>(b1, b2, b3, b4, (float*)(ws + BOFF));

    cnf_main<<<BATCH / 64, 512, SMEM_BYTES, stream>>>(x, eps, ws, out);
}